// Round 12
// baseline (220.370 us; speedup 1.0000x reference)
//
#include <hip/hip_runtime.h>
#include <math.h>

// MMD loss. Z = concat(X,Y) [8192 x 256] fp32.
// Round 20: R19 invalidated (2-slice buffers = 32KB each -> 128.5KB LDS ->
//   1 block/CU; that ring needs >=96KB and can never fit 2 blocks/CU).
//   Standing facts: k_gram floor ~48.5us (R13 structure); total - k_gram
//   ~= 63us FIXED across R8-R19 regardless of kernel count/grids -- i.e.
//   launch/drain overhead of the serial multi-kernel pipeline, never k_gram.
//   Fix: FUSE into one kernel. (1) work-stealing prep: global ticket hands
//   512 16-row chunks to whichever blocks run first (deadlock-free at any
//   residency); (2) finisher block computes c2 (same summation order via
//   coherent atomic reads -> bit-identical) and releases a device-scope
//   flag; (3) all blocks gate on the flag, then run R13's gram loop
//   VERBATIM. Release fences (threadfence = wbl2) before done-counts;
//   acquire fence after gate; g_zf/sq are iteration-invariant so stale-L2
//   lines hold identical bytes after iter 0. Prep scratch overlays the
//   64KB ring (used before ring's first write): 66KB LDS, 2 blocks/CU.
//   Spill canary moves: WRITE_SIZE ~4.3MB is legit prep writes; >5.5MB=spill.
// Math (R5-R19 verified, absmax 0.0): 1-phase bf16 Gram, sq exact fp32;
//   d2 = sq_i + sq_j - 2 z_i.z_j; bandwidth analytic
//   (sum d2 = 2M*S - 2||sum z||^2); K = t+t^2+t^4+t^8+t^16, t=exp(-d2/(4bw));
//   out = (Sxx + Syy - Sxy_both)/n^2, fp64 accumulation.

#define N_HALF 4096
#define DIM 256
#define M_TOT 8192
#define TILE 128
#define NT 64
#define NT_HALF 32
#define NCHUNK 512   // blocks; 480 do 4 tiles, 32 (cc%16==0) do 5: 2080 total
#define NPCHUNK 512  // prep chunks (16 rows each)
#define MAGIC 0x13371337u

typedef unsigned short ushort_t;
typedef __attribute__((ext_vector_type(8))) short short8;   // 8 bf16 = 4 VGPRs
typedef __attribute__((ext_vector_type(4))) float floatx4;  // MFMA C/D

// Fragment-swizzled bf16 Z (4 MB). For row-block rb (16 rows) and k-chunk kk
// (32 k): g_zf[rb*4096 + kk*512 + q*128 + m*8 + j] = Z[rb*16+m][kk*32+q*8+j].
// The 16B unit of lane (quad=q, l15=m) sits at byte lane*16 within the 1KB
// chunk: MFMA frag ds_read_b128 is linear in lane -> conflict-free; staging
// global_load_lds (dest base+lane*16, src +lane*16) is a pure linear copy.
__device__ ushort_t g_zf[M_TOT * DIM];

__device__ __forceinline__ ushort_t f2bf(float f) {  // RNE, finite inputs
    unsigned u = __float_as_uint(f);
    u += 0x7fffu + ((u >> 16) & 1u);
    return (ushort_t)(u >> 16);
}

__device__ __forceinline__ void gload_lds16(const ushort_t* g, ushort_t* l) {
    __builtin_amdgcn_global_load_lds(
        (const __attribute__((address_space(1))) void*)g,
        (__attribute__((address_space(3))) void*)l, 16, 0, 0);
}

// Stage one kk-slice (A 8KB + B 8KB) into one ring buffer.
// Wave w stages chunks {2w, 2w+1} of A and B: 4 gload_lds of 1KB per wave.
__device__ __forceinline__ void stage1(const ushort_t* gA, const ushort_t* gB,
                                       int kk, ushort_t* buf, int wave, int lane) {
#pragma unroll
    for (int i = 0; i < 2; ++i) {
        const int c = wave * 2 + i;
        gload_lds16(gA + (size_t)c * 4096 + kk * 512 + lane * 8, buf + c * 512);
        gload_lds16(gB + (size_t)c * 4096 + kk * 512 + lane * 8, buf + 4096 + c * 512);
    }
}

__device__ __forceinline__ unsigned norm_cnt(unsigned raw) {
    // ws poison base 0xAAAAAAAA or 0 — normalize either
    return (raw >= 0xAAAAAAAAu) ? raw - 0xAAAAAAAAu : raw;
}

// ---------------- k_all: fused prep + bandwidth + gram -----------------------
// 512 blocks x 256 threads = 2 blocks/CU (66 KB LDS, VGPR<=128).
__global__ __launch_bounds__(256, 2) void k_all(
        const float* __restrict__ X, const float* __restrict__ Y,
        float* __restrict__ sq, float* __restrict__ colsum_r,
        float* __restrict__ Ssum_r, unsigned* __restrict__ tkt,
        unsigned* __restrict__ done, unsigned* __restrict__ ready,
        float* __restrict__ c2ws, double* __restrict__ acc,
        unsigned* __restrict__ cnt, float* __restrict__ out) {
    // ring buf b: A slice [0,4096), B slice [4096,8192) ushorts (8 KB each).
    __shared__ __attribute__((aligned(16))) ushort_t lds[4][8192];
    __shared__ double redw[4][3];
    __shared__ int sh_chunk, sh_fin;
    __shared__ float sh_c2;

    const int t = threadIdx.x;
    const int lane = t & 63, wave = t >> 6;

    // ---------- phase 1: work-stealing prep (overlays ring as scratch) ------
    {
        float* cpart = (float*)&lds[0][0];   // [4][256] f32 = 4 KB
        float* spart = (float*)&lds[1][0];   // 4 f32
        double* sred = (double*)&lds[2][0];  // 4 f64
        const int kk = lane >> 3, q = (lane >> 1) & 3, j0 = (lane & 1) * 4;
        for (;;) {
            if (t == 0) {
                const unsigned nm = norm_cnt(atomicAdd(tkt, 1u));
                sh_chunk = (nm < (unsigned)NPCHUNK) ? (int)nm : -1;
            }
            __syncthreads();
            const int chunk = sh_chunk;
            if (chunk < 0) break;
            const int row0 = chunk * 16 + wave * 4;
            float s0 = 0.f, s1 = 0.f, s2 = 0.f, s3 = 0.f, ssum = 0.f;
#pragma unroll
            for (int i = 0; i < 4; ++i) {
                const int row = row0 + i;
                const float* p = (row < N_HALF)
                                     ? (X + (size_t)row * DIM)
                                     : (Y + (size_t)(row - N_HALF) * DIM);
                const float4 v = *((const float4*)p + lane);
                ushort4 hi;
                hi.x = f2bf(v.x); hi.y = f2bf(v.y);
                hi.z = f2bf(v.z); hi.w = f2bf(v.w);
                const int rb = row >> 4, m = row & 15;
                *(ushort4*)(g_zf + (size_t)rb * 4096 + kk * 512 + q * 128 +
                            m * 8 + j0) = hi;
                s0 += v.x; s1 += v.y; s2 += v.z; s3 += v.w;
                float s = fmaf(v.x, v.x,
                               fmaf(v.y, v.y, fmaf(v.z, v.z, v.w * v.w)));
#pragma unroll
                for (int off = 32; off > 0; off >>= 1) s += __shfl_xor(s, off);
                if (lane == 0) sq[row] = s;
                ssum += s;  // butterfly left full sum in every lane
            }
            float4 cp; cp.x = s0; cp.y = s1; cp.z = s2; cp.w = s3;
            *(float4*)&cpart[wave * 256 + lane * 4] = cp;
            if (lane == 0) spart[wave] = ssum;
            __syncthreads();
            const float cs = cpart[t] + cpart[256 + t] + cpart[512 + t] +
                             cpart[768 + t];
            const int rep = chunk & 7;  // same replica scheme as before
            atomicAdd(&colsum_r[rep * 256 + t], cs);
            if (t == 0) {
                atomicAdd(&Ssum_r[rep],
                          spart[0] + spart[1] + spart[2] + spart[3]);
                __threadfence();  // release chunk writes before done bump
                sh_fin = (norm_cnt(atomicAdd(done, 1u)) ==
                          (unsigned)(NPCHUNK - 1));
            }
            __syncthreads();
            if (sh_fin) {
                // finisher: bandwidth (identical summation order -> same c2)
                float csf = 0.f;
#pragma unroll
                for (int r = 0; r < 8; ++r)
                    csf += atomicAdd(&colsum_r[r * 256 + t], 0.f);
                double p = (double)csf * (double)csf;
#pragma unroll
                for (int off = 32; off > 0; off >>= 1) p += __shfl_xor(p, off);
                if (lane == 0) sred[wave] = p;
                __syncthreads();
                if (t == 0) {
                    const double SS = sred[0] + sred[1] + sred[2] + sred[3];
                    float Sf = 0.f;
#pragma unroll
                    for (int r = 0; r < 8; ++r)
                        Sf += atomicAdd(&Ssum_r[r], 0.f);
                    const double sum_d2 =
                        2.0 * (double)M_TOT * (double)Sf - 2.0 * SS;
                    const double bw = sum_d2 / ((double)M_TOT * (double)M_TOT -
                                                (double)M_TOT);
                    c2ws[0] = (float)(1.4426950408889634 / (4.0 * bw));
                    __threadfence();          // release c2 before flag
                    atomicExch(ready, MAGIC); // device-scope release
                }
            }
            __syncthreads();  // protect cpart reuse next iteration
        }
    }

    // ---------- gate: wait for all prep + c2 (deadlock-free: flag is set by
    // a RUNNING block; late-scheduled blocks see it already set) ------------
    if (t == 0) {
        while (atomicAdd(ready, 0u) != MAGIC) __builtin_amdgcn_s_sleep(2);
        sh_c2 = atomicAdd(c2ws, 0.0f);  // coherent read
    }
    __syncthreads();
    __threadfence();  // acquire: order g_zf/sq reads after the flag

    // ---------- phase 2: R13 gram loop (verbatim) ---------------------------
    // XCD-band swizzle (512 = 8*64): same-XCD blocks contiguous in triangle.
    const int bid = (int)blockIdx.x;
    const int cc = (bid & 7) * 64 + (bid >> 3);
    // 32 long blocks (cc%16==0 -> 4 per XCD) do 5 tiles; rest do 4.
    const int nst = ((cc & 15) == 0) ? 5 : 4;
    const int f0 = cc * 4 + ((cc + 15) >> 4);  // first flat tile of this block

    const int l15 = lane & 15, quad = lane >> 4;
    const int wrow = (wave >> 1) * 64, wcol = (wave & 1) * 64;
    const int a0 = (wave >> 1) * 4, b0 = (wave & 1) * 4;  // frag chunk bases
    const int laneoff = quad * 128 + l15 * 8;  // = lane*16B: linear

    const float c2 = sh_c2;
    const float twoc2 = 2.f * c2;

    // triangular decode of f0 -> (ti, tj), tj >= ti
    int ti = (int)((129.0f - sqrtf(16641.0f - 8.0f * (float)f0)) * 0.5f);
    if (ti < 0) ti = 0; if (ti > NT - 1) ti = NT - 1;
    while (ti * NT - ti * (ti - 1) / 2 > f0) --ti;
    while ((ti + 1) * NT - (ti + 1) * ti / 2 <= f0) ++ti;
    int tj = ti + (f0 - (ti * NT - ti * (ti - 1) / 2));

    // stage stream (runs 3 slices ahead of compute)
    int s_ti = ti, s_tj = tj, s_kk = 0;
    const ushort_t* sgA = g_zf + (size_t)s_ti * 32768;
    const ushort_t* sgB = g_zf + (size_t)s_tj * 32768;
#define ADV_STAGE() do { if (++s_kk == 8) { s_kk = 0; ++s_tj;                 \
        if (s_tj == NT) { ++s_ti; s_tj = s_ti; }                              \
        sgA = g_zf + (size_t)s_ti * 32768;                                    \
        sgB = g_zf + (size_t)s_tj * 32768; } } while (0)

    // prime slices 0,1,2 into bufs 0,1,2 (12 loads in flight per wave)
#pragma unroll
    for (int p = 0; p < 3; ++p) {
        stage1(sgA, sgB, s_kk, lds[p], wave, lane);
        ADV_STAGE();
    }

    double lxx = 0.0, lxy = 0.0, lyy = 0.0;

#pragma unroll 1
    for (int s = 0; s < nst; ++s) {
        const bool last = (s == nst - 1);

        floatx4 accv[4][4];
#pragma unroll
        for (int mi = 0; mi < 4; ++mi)
#pragma unroll
            for (int ni = 0; ni < 4; ++ni) accv[mi][ni] = (floatx4)0.f;

#pragma unroll
        for (int kkc = 0; kkc < 8; ++kkc) {
            // counted wait: slice about to be read (4 loads) is complete once
            // <=8 outstanding (in-order retire).
            if (last && kkc == 6)      asm volatile("s_waitcnt vmcnt(4)" ::: "memory");
            else if (last && kkc == 7) asm volatile("s_waitcnt vmcnt(0)" ::: "memory");
            else                       asm volatile("s_waitcnt vmcnt(8)" ::: "memory");
            __builtin_amdgcn_s_barrier();
            __builtin_amdgcn_sched_barrier(0);

            const ushort_t* lA = lds[kkc & 3];
            const ushort_t* lB = lds[kkc & 3] + 4096;
            short8 af[4], bf[4];
#pragma unroll
            for (int mi = 0; mi < 4; ++mi)
                af[mi] = *(const short8*)(lA + (a0 + mi) * 512 + laneoff);
#pragma unroll
            for (int ni = 0; ni < 4; ++ni)
                bf[ni] = *(const short8*)(lB + (b0 + ni) * 512 + laneoff);

            // issue stage of slice g+3 into buf (g+3)&3 (consumed at phase
            // g-1; all waves passed this phase's barrier after reading it)
            if (!last || kkc < 5) {
                stage1(sgA, sgB, s_kk, lds[(kkc + 3) & 3], wave, lane);
                ADV_STAGE();
            }

            __builtin_amdgcn_s_setprio(1);
#pragma unroll
            for (int mi = 0; mi < 4; ++mi)
#pragma unroll
                for (int ni = 0; ni < 4; ++ni)
                    accv[mi][ni] = __builtin_amdgcn_mfma_f32_16x16x32_bf16(
                        af[mi], bf[ni], accv[mi][ni], 0, 0, 0);
            __builtin_amdgcn_s_setprio(0);
        }

        // ---- epilogue for (ti, tj). C/D: col = lane&15, row = quad*4+reg.
        const int arow0 = ti * TILE, brow0 = tj * TILE;
        float nsj[4];
#pragma unroll
        for (int ni = 0; ni < 4; ++ni)
            nsj[ni] = -c2 * sq[brow0 + wcol + ni * 16 + l15];
        floatx4 nsi4[4];
#pragma unroll
        for (int mi = 0; mi < 4; ++mi) {
            const float4 sv = *(const float4*)&sq[arow0 + wrow + mi * 16 + quad * 4];
            nsi4[mi][0] = -c2 * sv.x; nsi4[mi][1] = -c2 * sv.y;
            nsi4[mi][2] = -c2 * sv.z; nsi4[mi][3] = -c2 * sv.w;
        }
        floatx4 sum4 = (floatx4)0.f;
#pragma unroll
        for (int mi = 0; mi < 4; ++mi) {
#pragma unroll
            for (int ni = 0; ni < 4; ++ni) {
                const floatx4 addv = nsi4[mi] + (floatx4)nsj[ni];
                floatx4 arg = twoc2 * accv[mi][ni] + addv;
                floatx4 tt;
#pragma unroll
                for (int r = 0; r < 4; ++r) tt[r] = exp2f(fminf(arg[r], 0.f));
                const floatx4 t2 = tt * tt, t4 = t2 * t2, t8 = t4 * t4, t16 = t8 * t8;
                sum4 += (tt + t2) + (t4 + t8) + t16;
            }
        }
        const float fsum = (sum4[0] + sum4[1]) + (sum4[2] + sum4[3]);
        const double contrib = ((ti == tj) ? 1.0 : 2.0) * (double)fsum;
        if (tj < NT_HALF)       lxx += contrib;   // block-uniform branches
        else if (ti < NT_HALF)  lxy += contrib;
        else                    lyy += contrib;

        // advance compute tile
        ++tj; if (tj == NT) { ++ti; tj = ti; }
    }
#undef ADV_STAGE

    // ---- block reduction + finalize ----
#pragma unroll
    for (int off = 32; off > 0; off >>= 1) {
        lxx += __shfl_xor(lxx, off);
        lxy += __shfl_xor(lxy, off);
        lyy += __shfl_xor(lyy, off);
    }
    if (lane == 0) { redw[wave][0] = lxx; redw[wave][1] = lxy; redw[wave][2] = lyy; }
    __syncthreads();
    if (t == 0) {
        double sxx = 0.0, sxy = 0.0, syy = 0.0;
#pragma unroll
        for (int wv = 0; wv < 4; ++wv) {
            sxx += redw[wv][0]; sxy += redw[wv][1]; syy += redw[wv][2];
        }
        if (sxx != 0.0) atomicAdd(&acc[0], sxx);
        if (sxy != 0.0) atomicAdd(&acc[1], sxy);
        if (syy != 0.0) atomicAdd(&acc[2], syy);
        __threadfence();  // release region adds before counter bump
        const unsigned old = atomicAdd(cnt, 1u);
        if (norm_cnt(old) == (unsigned)(NCHUNK - 1)) {
            const double xx = atomicAdd(&acc[0], 0.0);  // coherent reads
            const double xy = atomicAdd(&acc[1], 0.0);
            const double yy = atomicAdd(&acc[2], 0.0);
            out[0] = (float)((xx + yy - xy) *
                             (1.0 / ((double)N_HALF * (double)N_HALF)));
        }
    }
}

extern "C" void kernel_launch(void* const* d_in, const int* in_sizes, int n_in,
                              void* d_out, int out_size, void* d_ws, size_t ws_size,
                              hipStream_t stream) {
    const float* X = (const float*)d_in[0];
    const float* Y = (const float*)d_in[1];
    char* ws = (char*)d_ws;
    float* sq        = (float*)ws;               // 8192 f32  [0, 32768)
    float* colsum_r  = (float*)(ws + 32768);     // 8*256 f32 [32768, 40960)
    float* Ssum_r    = (float*)(ws + 40960);     // 8 f32     [40960, 40992)
    unsigned* cnt    = (unsigned*)(ws + 40992);  // 1 u32 (gram finalize)
    double* acc      = (double*)(ws + 41000);    // 3 f64 (8-aligned)
    float* c2ws      = (float*)(ws + 41024);     // 1 f32
    unsigned* tkt    = (unsigned*)(ws + 41028);  // prep ticket counter
    unsigned* done   = (unsigned*)(ws + 41032);  // prep done counter
    unsigned* ready  = (unsigned*)(ws + 41036);  // c2-ready flag
    float* out = (float*)d_out;

    hipLaunchKernelGGL(k_all, dim3(NCHUNK), dim3(256), 0, stream,
                       X, Y, sq, colsum_r, Ssum_r, tkt, done, ready,
                       c2ws, acc, cnt, out);
}

// Round 14
// 213.929 us; speedup vs baseline: 1.0301x; 1.0301x over previous
//
#include <hip/hip_runtime.h>
#include <math.h>

// MMD loss. Z = concat(X,Y) [8192 x 256] fp32.
// Round 22: R21 cooperative launch failed (absmax == plausible |ref| => launch
//   rejected under graph capture, out stayed 0). R20 already HW-validated the
//   fused semantics (absmax 0.0); its 140us overhead was the gate spin using
//   device-scope atomicAdd RMW on ONE line from 512 blocks (RMWs serialize at
//   L3, ~150us/round). Fix: same fused structure, spin via agent-scope atomic
//   LOAD (bypasses non-coherent L2, reads L3, loads don't serialize) +
//   s_sleep(8) backoff. chunk = blockIdx (no tickets); release side keeps
//   R20's validated store->threadfence->atomicExch. Post-gate __threadfence
//   drains vmcnt=0 so phase-3's counted-vmcnt proof starts clean. Idempotent
//   under missing re-poison (flag stays MAGIC -> skip gate; all bytes
//   republished bit-identical).
// Math (R5-R20 verified, absmax 0.0): 1-phase bf16 Gram, sq exact fp32;
//   d2 = sq_i + sq_j - 2 z_i.z_j; bandwidth analytic
//   (sum d2 = 2M*S - 2||sum z||^2); K = t+t^2+t^4+t^8+t^16, t=exp(-d2/(4bw));
//   out = (Sxx + Syy - Sxy_both)/n^2, fp64 accumulation.

#define N_HALF 4096
#define DIM 256
#define M_TOT 8192
#define TILE 128
#define NT 64
#define NT_HALF 32
#define NCHUNK 512   // blocks; 480 do 4 tiles, 32 (cc%16==0) do 5: 2080 total
#define NPCHUNK 512  // prep chunks (16 rows each; chunk = blockIdx)
#define MAGIC 0x13371337u

typedef unsigned short ushort_t;
typedef __attribute__((ext_vector_type(8))) short short8;   // 8 bf16 = 4 VGPRs
typedef __attribute__((ext_vector_type(4))) float floatx4;  // MFMA C/D

// Fragment-swizzled bf16 Z (4 MB). For row-block rb (16 rows) and k-chunk kk
// (32 k): g_zf[rb*4096 + kk*512 + q*128 + m*8 + j] = Z[rb*16+m][kk*32+q*8+j].
// The 16B unit of lane (quad=q, l15=m) sits at byte lane*16 within the 1KB
// chunk: MFMA frag ds_read_b128 is linear in lane -> conflict-free; staging
// global_load_lds (dest base+lane*16, src +lane*16) is a pure linear copy.
__device__ ushort_t g_zf[M_TOT * DIM];

__device__ __forceinline__ ushort_t f2bf(float f) {  // RNE, finite inputs
    unsigned u = __float_as_uint(f);
    u += 0x7fffu + ((u >> 16) & 1u);
    return (ushort_t)(u >> 16);
}

__device__ __forceinline__ void gload_lds16(const ushort_t* g, ushort_t* l) {
    __builtin_amdgcn_global_load_lds(
        (const __attribute__((address_space(1))) void*)g,
        (__attribute__((address_space(3))) void*)l, 16, 0, 0);
}

// Stage one kk-slice (A 8KB + B 8KB) into one ring buffer.
// Wave w stages chunks {2w, 2w+1} of A and B: 4 gload_lds of 1KB per wave.
__device__ __forceinline__ void stage1(const ushort_t* gA, const ushort_t* gB,
                                       int kk, ushort_t* buf, int wave, int lane) {
#pragma unroll
    for (int i = 0; i < 2; ++i) {
        const int c = wave * 2 + i;
        gload_lds16(gA + (size_t)c * 4096 + kk * 512 + lane * 8, buf + c * 512);
        gload_lds16(gB + (size_t)c * 4096 + kk * 512 + lane * 8, buf + 4096 + c * 512);
    }
}

__device__ __forceinline__ unsigned norm_cnt(unsigned raw) {
    // ws poison base 0xAAAAAAAA or 0 — normalize either
    return (raw >= 0xAAAAAAAAu) ? raw - 0xAAAAAAAAu : raw;
}

// ---------------- k_all: fused prep + flag gate + bw + gram ------------------
// 512 blocks x 256 threads = 2 blocks/CU (68.3 KB LDS, VGPR<=128).
__global__ __launch_bounds__(256, 2) void k_all(
        const float* __restrict__ X, const float* __restrict__ Y,
        float* __restrict__ sq, float* __restrict__ colsum_r,
        float* __restrict__ Ssum_r, unsigned* __restrict__ done,
        unsigned* __restrict__ ready, float* __restrict__ c2ws,
        double* __restrict__ acc, unsigned* __restrict__ cnt,
        float* __restrict__ out) {
    // ring buf b: A slice [0,4096), B slice [4096,8192) ushorts (8 KB each).
    __shared__ __attribute__((aligned(16))) ushort_t lds[4][8192];
    __shared__ float cpart[4][256];   // prep scratch (4 KB, separate from ring)
    __shared__ float spart[4];
    __shared__ double redw[4][3];
    __shared__ int sh_fin;
    __shared__ float sh_c2;

    const int t = threadIdx.x;
    const int lane = t & 63, wave = t >> 6;

    // ---------- phase 1: prep (chunk = blockIdx.x, 16 rows) -----------------
    {
        const int kk = lane >> 3, q = (lane >> 1) & 3, j0 = (lane & 1) * 4;
        const int row0 = (int)blockIdx.x * 16 + wave * 4;
        float s0 = 0.f, s1 = 0.f, s2 = 0.f, s3 = 0.f, ssum = 0.f;
#pragma unroll
        for (int i = 0; i < 4; ++i) {
            const int row = row0 + i;
            const float* p = (row < N_HALF) ? (X + (size_t)row * DIM)
                                            : (Y + (size_t)(row - N_HALF) * DIM);
            const float4 v = *((const float4*)p + lane);
            ushort4 hi;
            hi.x = f2bf(v.x); hi.y = f2bf(v.y); hi.z = f2bf(v.z); hi.w = f2bf(v.w);
            const int rb = row >> 4, m = row & 15;
            *(ushort4*)(g_zf + (size_t)rb * 4096 + kk * 512 + q * 128 + m * 8 + j0) = hi;
            s0 += v.x; s1 += v.y; s2 += v.z; s3 += v.w;
            float s = fmaf(v.x, v.x, fmaf(v.y, v.y, fmaf(v.z, v.z, v.w * v.w)));
#pragma unroll
            for (int off = 32; off > 0; off >>= 1) s += __shfl_xor(s, off);
            if (lane == 0) sq[row] = s;
            ssum += s;  // butterfly left full sum in every lane
        }
        float4 cp; cp.x = s0; cp.y = s1; cp.z = s2; cp.w = s3;
        *(float4*)&cpart[wave][lane * 4] = cp;
        if (lane == 0) spart[wave] = ssum;
        __syncthreads();
        const float cs = cpart[0][t] + cpart[1][t] + cpart[2][t] + cpart[3][t];
        const int rep = (int)blockIdx.x & 7;  // 8 replicas -> 64 adds/address
        atomicAdd(&colsum_r[rep * 256 + t], cs);
        if (t == 0) {
            atomicAdd(&Ssum_r[rep], spart[0] + spart[1] + spart[2] + spart[3]);
            __threadfence();  // release: wb this block's g_zf/sq before bump
            sh_fin = (norm_cnt(atomicAdd(done, 1u)) == (unsigned)(NPCHUNK - 1));
        }
        __syncthreads();
        if (sh_fin) {
            // finisher: bandwidth (identical summation order -> identical c2)
            float csf = 0.f;
#pragma unroll
            for (int r = 0; r < 8; ++r)
                csf += atomicAdd(&colsum_r[r * 256 + t], 0.f);
            double p = (double)csf * (double)csf;
#pragma unroll
            for (int off = 32; off > 0; off >>= 1) p += __shfl_xor(p, off);
            if (lane == 0) redw[wave][0] = p;
            __syncthreads();
            if (t == 0) {
                const double SS = redw[0][0] + redw[1][0] + redw[2][0] + redw[3][0];
                float Sf = 0.f;
#pragma unroll
                for (int r = 0; r < 8; ++r) Sf += atomicAdd(&Ssum_r[r], 0.f);
                const double sum_d2 = 2.0 * (double)M_TOT * (double)Sf - 2.0 * SS;
                const double bw = sum_d2 / ((double)M_TOT * (double)M_TOT -
                                            (double)M_TOT);
                c2ws[0] = (float)(1.4426950408889634 / (4.0 * bw));
                __threadfence();          // release c2 before flag
                atomicExch(ready, MAGIC); // device-scope release (validated R20)
            }
        }
    }

    // ---------- gate: agent-scope atomic LOAD spin (no RMW serialization) ---
    if (t == 0) {
        while (__hip_atomic_load(ready, __ATOMIC_ACQUIRE,
                                 __HIP_MEMORY_SCOPE_AGENT) != MAGIC)
            __builtin_amdgcn_s_sleep(8);
        sh_c2 = atomicAdd(c2ws, 0.0f);  // coherent read (validated R20)
    }
    __syncthreads();
    __threadfence();  // acquire + drains vmcnt=0 for phase-3 counted waits

    // ---------- phase 3: R13 gram loop (verbatim) ---------------------------
    // XCD-band swizzle (512 = 8*64): same-XCD blocks contiguous in triangle.
    const int bid = (int)blockIdx.x;
    const int cc = (bid & 7) * 64 + (bid >> 3);
    // 32 long blocks (cc%16==0 -> 4 per XCD) do 5 tiles; rest do 4.
    const int nst = ((cc & 15) == 0) ? 5 : 4;
    const int f0 = cc * 4 + ((cc + 15) >> 4);  // first flat tile of this block

    const int l15 = lane & 15, quad = lane >> 4;
    const int wrow = (wave >> 1) * 64, wcol = (wave & 1) * 64;
    const int a0 = (wave >> 1) * 4, b0 = (wave & 1) * 4;  // frag chunk bases
    const int laneoff = quad * 128 + l15 * 8;  // = lane*16B: linear

    const float c2 = sh_c2;
    const float twoc2 = 2.f * c2;

    // triangular decode of f0 -> (ti, tj), tj >= ti
    int ti = (int)((129.0f - sqrtf(16641.0f - 8.0f * (float)f0)) * 0.5f);
    if (ti < 0) ti = 0; if (ti > NT - 1) ti = NT - 1;
    while (ti * NT - ti * (ti - 1) / 2 > f0) --ti;
    while ((ti + 1) * NT - (ti + 1) * ti / 2 <= f0) ++ti;
    int tj = ti + (f0 - (ti * NT - ti * (ti - 1) / 2));

    // stage stream (runs 3 slices ahead of compute)
    int s_ti = ti, s_tj = tj, s_kk = 0;
    const ushort_t* sgA = g_zf + (size_t)s_ti * 32768;
    const ushort_t* sgB = g_zf + (size_t)s_tj * 32768;
#define ADV_STAGE() do { if (++s_kk == 8) { s_kk = 0; ++s_tj;                 \
        if (s_tj == NT) { ++s_ti; s_tj = s_ti; }                              \
        sgA = g_zf + (size_t)s_ti * 32768;                                    \
        sgB = g_zf + (size_t)s_tj * 32768; } } while (0)

    // prime slices 0,1,2 into bufs 0,1,2 (12 loads in flight per wave)
#pragma unroll
    for (int p = 0; p < 3; ++p) {
        stage1(sgA, sgB, s_kk, lds[p], wave, lane);
        ADV_STAGE();
    }

    double lxx = 0.0, lxy = 0.0, lyy = 0.0;

#pragma unroll 1
    for (int s = 0; s < nst; ++s) {
        const bool last = (s == nst - 1);

        floatx4 accv[4][4];
#pragma unroll
        for (int mi = 0; mi < 4; ++mi)
#pragma unroll
            for (int ni = 0; ni < 4; ++ni) accv[mi][ni] = (floatx4)0.f;

#pragma unroll
        for (int kkc = 0; kkc < 8; ++kkc) {
            // counted wait: slice about to be read (4 loads) is complete once
            // <=8 outstanding (in-order retire).
            if (last && kkc == 6)      asm volatile("s_waitcnt vmcnt(4)" ::: "memory");
            else if (last && kkc == 7) asm volatile("s_waitcnt vmcnt(0)" ::: "memory");
            else                       asm volatile("s_waitcnt vmcnt(8)" ::: "memory");
            __builtin_amdgcn_s_barrier();
            __builtin_amdgcn_sched_barrier(0);

            const ushort_t* lA = lds[kkc & 3];
            const ushort_t* lB = lds[kkc & 3] + 4096;
            short8 af[4], bf[4];
#pragma unroll
            for (int mi = 0; mi < 4; ++mi)
                af[mi] = *(const short8*)(lA + (a0 + mi) * 512 + laneoff);
#pragma unroll
            for (int ni = 0; ni < 4; ++ni)
                bf[ni] = *(const short8*)(lB + (b0 + ni) * 512 + laneoff);

            // issue stage of slice g+3 into buf (g+3)&3 (consumed at phase
            // g-1; all waves passed this phase's barrier after reading it)
            if (!last || kkc < 5) {
                stage1(sgA, sgB, s_kk, lds[(kkc + 3) & 3], wave, lane);
                ADV_STAGE();
            }

            __builtin_amdgcn_s_setprio(1);
#pragma unroll
            for (int mi = 0; mi < 4; ++mi)
#pragma unroll
                for (int ni = 0; ni < 4; ++ni)
                    accv[mi][ni] = __builtin_amdgcn_mfma_f32_16x16x32_bf16(
                        af[mi], bf[ni], accv[mi][ni], 0, 0, 0);
            __builtin_amdgcn_s_setprio(0);
        }

        // ---- epilogue for (ti, tj). C/D: col = lane&15, row = quad*4+reg.
        const int arow0 = ti * TILE, brow0 = tj * TILE;
        float nsj[4];
#pragma unroll
        for (int ni = 0; ni < 4; ++ni)
            nsj[ni] = -c2 * sq[brow0 + wcol + ni * 16 + l15];
        floatx4 nsi4[4];
#pragma unroll
        for (int mi = 0; mi < 4; ++mi) {
            const float4 sv = *(const float4*)&sq[arow0 + wrow + mi * 16 + quad * 4];
            nsi4[mi][0] = -c2 * sv.x; nsi4[mi][1] = -c2 * sv.y;
            nsi4[mi][2] = -c2 * sv.z; nsi4[mi][3] = -c2 * sv.w;
        }
        floatx4 sum4 = (floatx4)0.f;
#pragma unroll
        for (int mi = 0; mi < 4; ++mi) {
#pragma unroll
            for (int ni = 0; ni < 4; ++ni) {
                const floatx4 addv = nsi4[mi] + (floatx4)nsj[ni];
                floatx4 arg = twoc2 * accv[mi][ni] + addv;
                floatx4 tt;
#pragma unroll
                for (int r = 0; r < 4; ++r) tt[r] = exp2f(fminf(arg[r], 0.f));
                const floatx4 t2 = tt * tt, t4 = t2 * t2, t8 = t4 * t4, t16 = t8 * t8;
                sum4 += (tt + t2) + (t4 + t8) + t16;
            }
        }
        const float fsum = (sum4[0] + sum4[1]) + (sum4[2] + sum4[3]);
        const double contrib = ((ti == tj) ? 1.0 : 2.0) * (double)fsum;
        if (tj < NT_HALF)       lxx += contrib;   // block-uniform branches
        else if (ti < NT_HALF)  lxy += contrib;
        else                    lyy += contrib;

        // advance compute tile
        ++tj; if (tj == NT) { ++ti; tj = ti; }
    }
#undef ADV_STAGE

    // ---- block reduction + finalize ----
#pragma unroll
    for (int off = 32; off > 0; off >>= 1) {
        lxx += __shfl_xor(lxx, off);
        lxy += __shfl_xor(lxy, off);
        lyy += __shfl_xor(lyy, off);
    }
    if (lane == 0) { redw[wave][0] = lxx; redw[wave][1] = lxy; redw[wave][2] = lyy; }
    __syncthreads();
    if (t == 0) {
        double sxx = 0.0, sxy = 0.0, syy = 0.0;
#pragma unroll
        for (int wv = 0; wv < 4; ++wv) {
            sxx += redw[wv][0]; sxy += redw[wv][1]; syy += redw[wv][2];
        }
        if (sxx != 0.0) atomicAdd(&acc[0], sxx);
        if (sxy != 0.0) atomicAdd(&acc[1], sxy);
        if (syy != 0.0) atomicAdd(&acc[2], syy);
        __threadfence();  // release region adds before counter bump
        const unsigned old = atomicAdd(cnt, 1u);
        if (norm_cnt(old) == (unsigned)(NCHUNK - 1)) {
            const double xx = atomicAdd(&acc[0], 0.0);  // coherent reads
            const double xy = atomicAdd(&acc[1], 0.0);
            const double yy = atomicAdd(&acc[2], 0.0);
            out[0] = (float)((xx + yy - xy) *
                             (1.0 / ((double)N_HALF * (double)N_HALF)));
        }
    }
}

extern "C" void kernel_launch(void* const* d_in, const int* in_sizes, int n_in,
                              void* d_out, int out_size, void* d_ws, size_t ws_size,
                              hipStream_t stream) {
    const float* X = (const float*)d_in[0];
    const float* Y = (const float*)d_in[1];
    char* ws = (char*)d_ws;
    float* sq        = (float*)ws;               // 8192 f32  [0, 32768)
    float* colsum_r  = (float*)(ws + 32768);     // 8*256 f32 [32768, 40960)
    float* Ssum_r    = (float*)(ws + 40960);     // 8 f32     [40960, 40992)
    unsigned* cnt    = (unsigned*)(ws + 40992);  // 1 u32 (gram finalize)
    double* acc      = (double*)(ws + 41000);    // 3 f64 (8-aligned)
    float* c2ws      = (float*)(ws + 41024);     // 1 f32
    unsigned* done   = (unsigned*)(ws + 41028);  // prep done counter
    unsigned* ready  = (unsigned*)(ws + 41032);  // c2-ready flag
    float* out = (float*)d_out;

    hipLaunchKernelGGL(k_all, dim3(NCHUNK), dim3(256), 0, stream,
                       X, Y, sq, colsum_r, Ssum_r, done, ready,
                       c2ws, acc, cnt, out);
}

// Round 15
// 116.881 us; speedup vs baseline: 1.8854x; 1.8303x over previous
//
#include <hip/hip_runtime.h>
#include <math.h>

// MMD loss. Z = concat(X,Y) [8192 x 256] fp32.
// Round 23: R22 fused dispatch = 180us even with load-spin => the ~130us gate
//   cost is cross-XCD flag propagation (non-coherent L2s), not RMW. Fusion
//   abandoned; revert to proven 3-kernel layout (R13 = 48.5us k_gram).
//   k_gram lever never legally exercised: occupancy. R13-R17 all ran 2
//   waves/SIMD (64-VGPR acc blocked more; R18's (256,4) spilled). Fix:
//   HALVE the per-wave tile: 8 waves x 64x32 per 128^2 tile -> acc 32 VGPR,
//   frags 24, total ~110 fits a 128-reg budget -> __launch_bounds__(512,4)
//   = 2 x 8-wave blocks/CU = 4 waves/SIMD (2x latency cover). R13's ring /
//   counted-vmcnt structure verbatim; per-wave staging = 2 loads/slice ->
//   waits vmcnt(4)/2/0 (same in-order-retire proof); LDS 64.2KB <= 80KB.
//   Canaries: VGPR 100-126 & WRITE ~34KB (VGPR<=64 or WRITE MB = invalid).
// Math (R5-R22 verified, absmax 0.0): 1-phase bf16 Gram, sq exact fp32;
//   d2 = sq_i + sq_j - 2 z_i.z_j; bandwidth analytic
//   (sum d2 = 2M*S - 2||sum z||^2); K = t+t^2+t^4+t^8+t^16, t=exp(-d2/(4bw));
//   out = (Sxx + Syy - Sxy_both)/n^2, fp64 accumulation.

#define N_HALF 4096
#define DIM 256
#define M_TOT 8192
#define TILE 128
#define NT 64
#define NT_HALF 32
#define NCHUNK 512  // blocks; 480 do 4 tiles, 32 (cc%16==0) do 5: 2080 total

typedef unsigned short ushort_t;
typedef __attribute__((ext_vector_type(8))) short short8;   // 8 bf16 = 4 VGPRs
typedef __attribute__((ext_vector_type(4))) float floatx4;  // MFMA C/D

// Fragment-swizzled bf16 Z (4 MB). For row-block rb (16 rows) and k-chunk kk
// (32 k): g_zf[rb*4096 + kk*512 + q*128 + m*8 + j] = Z[rb*16+m][kk*32+q*8+j].
// The 16B unit of lane (quad=q, l15=m) sits at byte lane*16 within the 1KB
// chunk: MFMA frag ds_read_b128 is linear in lane -> conflict-free; staging
// global_load_lds (dest base+lane*16, src +lane*16) is a pure linear copy.
__device__ ushort_t g_zf[M_TOT * DIM];

__device__ __forceinline__ ushort_t f2bf(float f) {  // RNE, finite inputs
    unsigned u = __float_as_uint(f);
    u += 0x7fffu + ((u >> 16) & 1u);
    return (ushort_t)(u >> 16);
}

__device__ __forceinline__ void gload_lds16(const ushort_t* g, ushort_t* l) {
    __builtin_amdgcn_global_load_lds(
        (const __attribute__((address_space(1))) void*)g,
        (__attribute__((address_space(3))) void*)l, 16, 0, 0);
}

// Stage one kk-slice (A 8KB + B 8KB) into one ring buffer; 8 waves, wave w
// stages A chunk w and B chunk w: 2 gload_lds of 1KB per wave.
__device__ __forceinline__ void stage1(const ushort_t* gA, const ushort_t* gB,
                                       int kk, ushort_t* buf, int wave, int lane) {
    gload_lds16(gA + (size_t)wave * 4096 + kk * 512 + lane * 8, buf + wave * 512);
    gload_lds16(gB + (size_t)wave * 4096 + kk * 512 + lane * 8,
                buf + 4096 + wave * 512);
}

// ---------------- k_prep: convert(swizzled) + row norms + col sums -----------
// 512 blocks x 256 threads; wave w owns 4 rows; lane l owns cols [4l,4l+4).
__global__ __launch_bounds__(256) void k_prep(const float* __restrict__ X,
                                              const float* __restrict__ Y,
                                              float* __restrict__ sq,
                                              float* __restrict__ colsum_r,
                                              float* __restrict__ Ssum_r) {
    __shared__ float cpart[4][256];
    __shared__ float spart[4];
    const int t = threadIdx.x, wave = t >> 6, lane = t & 63;
    const int row0 = blockIdx.x * 16 + wave * 4;
    // swizzle coords for this lane's 4 columns [4l, 4l+4)
    const int kk = lane >> 3, q = (lane >> 1) & 3, j0 = (lane & 1) * 4;
    float c0 = 0.f, c1 = 0.f, c2 = 0.f, c3 = 0.f, ssum = 0.f;
#pragma unroll
    for (int i = 0; i < 4; ++i) {
        const int row = row0 + i;
        const float* p = (row < N_HALF) ? (X + (size_t)row * DIM)
                                        : (Y + (size_t)(row - N_HALF) * DIM);
        const float4 v = *((const float4*)p + lane);
        ushort4 hi;
        hi.x = f2bf(v.x); hi.y = f2bf(v.y); hi.z = f2bf(v.z); hi.w = f2bf(v.w);
        const int rb = row >> 4, m = row & 15;
        *(ushort4*)(g_zf + (size_t)rb * 4096 + kk * 512 + q * 128 + m * 8 + j0) = hi;
        c0 += v.x; c1 += v.y; c2 += v.z; c3 += v.w;
        float s = fmaf(v.x, v.x, fmaf(v.y, v.y, fmaf(v.z, v.z, v.w * v.w)));
#pragma unroll
        for (int off = 32; off > 0; off >>= 1) s += __shfl_xor(s, off);
        if (lane == 0) sq[row] = s;
        ssum += s;  // butterfly left full sum in every lane
    }
    float4 cp; cp.x = c0; cp.y = c1; cp.z = c2; cp.w = c3;
    *(float4*)&cpart[wave][lane * 4] = cp;
    if (lane == 0) spart[wave] = ssum;
    __syncthreads();
    const float cs = cpart[0][t] + cpart[1][t] + cpart[2][t] + cpart[3][t];
    const int rep = blockIdx.x & 7;  // 8 replicas -> 64 adds/address
    atomicAdd(&colsum_r[rep * 256 + t], cs);  // poison -3e-13/rep: harmless
    if (t == 0) atomicAdd(&Ssum_r[rep], spart[0] + spart[1] + spart[2] + spart[3]);
}

// ---------------- k_bw: one block computes exp2 scale c2 once ----------------
// Same summation order as the old per-block prologue -> bit-identical c2.
__global__ __launch_bounds__(256) void k_bw(const float* __restrict__ colsum_r,
                                            const float* __restrict__ Ssum_r,
                                            float* __restrict__ c2out) {
    __shared__ double sred[4];
    const int t = threadIdx.x, lane = t & 63, wave = t >> 6;
    float csf = 0.f;
#pragma unroll
    for (int r = 0; r < 8; ++r) csf += colsum_r[r * 256 + t];
    double p = (double)csf * (double)csf;
#pragma unroll
    for (int off = 32; off > 0; off >>= 1) p += __shfl_xor(p, off);
    if (lane == 0) sred[wave] = p;
    __syncthreads();
    if (t == 0) {
        const double SS = sred[0] + sred[1] + sred[2] + sred[3];
        float Sf = 0.f;
#pragma unroll
        for (int r = 0; r < 8; ++r) Sf += Ssum_r[r];
        const double sum_d2 = 2.0 * (double)M_TOT * (double)Sf - 2.0 * SS;
        const double bw = sum_d2 / ((double)M_TOT * (double)M_TOT - (double)M_TOT);
        c2out[0] = (float)(1.4426950408889634 / (4.0 * bw));  // exp2 scale
    }
}

// ---------------- k_gram: 8-wave counted-vmcnt ring MFMA Gram ----------------
// 512 blocks x 512 threads; 8 waves x (64x32) per 128^2 tile; acc 32 VGPR ->
// 128-reg budget -> 2 blocks/CU = 4 waves/SIMD (2x the latency cover of all
// prior variants). 4x16KB LDS ring, stage 3 slices ahead, vmcnt(4)/2/0.
__global__ __launch_bounds__(512, 4) void k_gram(const float* __restrict__ sq,
                                                 const float* __restrict__ c2p,
                                                 double* __restrict__ acc,
                                                 unsigned* __restrict__ cnt,
                                                 float* __restrict__ out) {
    // ring buf b: A slice [0,4096), B slice [4096,8192) ushorts (8 KB each).
    __shared__ __attribute__((aligned(16))) ushort_t lds[4][8192];
    __shared__ double redw[8][3];

    // XCD-band swizzle (512 = 8*64): same-XCD blocks contiguous in triangle.
    const int bid = (int)blockIdx.x;
    const int cc = (bid & 7) * 64 + (bid >> 3);
    // 32 long blocks (cc%16==0 -> 4 per XCD) do 5 tiles; rest do 4.
    const int nst = ((cc & 15) == 0) ? 5 : 4;
    const int f0 = cc * 4 + ((cc + 15) >> 4);  // first flat tile of this block

    const int t = threadIdx.x;
    const int lane = t & 63, wave = t >> 6;            // wave in [0,8)
    const int l15 = lane & 15, quad = lane >> 4;
    const int wrow = (wave >> 2) * 64, wcol = (wave & 3) * 32;
    const int a0 = (wave >> 2) * 4, b0 = (wave & 3) * 2;  // frag chunk bases
    const int laneoff = quad * 128 + l15 * 8;  // = lane*16B: linear, no conflict

    const float c2 = c2p[0];  // wave-uniform scalar load
    const float twoc2 = 2.f * c2;

    // triangular decode of f0 -> (ti, tj), tj >= ti
    int ti = (int)((129.0f - sqrtf(16641.0f - 8.0f * (float)f0)) * 0.5f);
    if (ti < 0) ti = 0; if (ti > NT - 1) ti = NT - 1;
    while (ti * NT - ti * (ti - 1) / 2 > f0) --ti;
    while ((ti + 1) * NT - (ti + 1) * ti / 2 <= f0) ++ti;
    int tj = ti + (f0 - (ti * NT - ti * (ti - 1) / 2));

    // stage stream (runs 3 slices ahead of compute)
    int s_ti = ti, s_tj = tj, s_kk = 0;
    const ushort_t* sgA = g_zf + (size_t)s_ti * 32768;
    const ushort_t* sgB = g_zf + (size_t)s_tj * 32768;
#define ADV_STAGE() do { if (++s_kk == 8) { s_kk = 0; ++s_tj;                 \
        if (s_tj == NT) { ++s_ti; s_tj = s_ti; }                              \
        sgA = g_zf + (size_t)s_ti * 32768;                                    \
        sgB = g_zf + (size_t)s_tj * 32768; } } while (0)

    // prime slices 0,1,2 into bufs 0,1,2 (6 loads in flight per wave)
#pragma unroll
    for (int p = 0; p < 3; ++p) {
        stage1(sgA, sgB, s_kk, lds[p], wave, lane);
        ADV_STAGE();
    }

    double lxx = 0.0, lxy = 0.0, lyy = 0.0;

#pragma unroll 1
    for (int s = 0; s < nst; ++s) {
        const bool last = (s == nst - 1);

        floatx4 accv[4][2];
#pragma unroll
        for (int mi = 0; mi < 4; ++mi)
#pragma unroll
            for (int ni = 0; ni < 2; ++ni) accv[mi][ni] = (floatx4)0.f;

#pragma unroll
        for (int kkc = 0; kkc < 8; ++kkc) {
            // counted wait: slice about to be read (2 loads/wave) is complete
            // once <=4 outstanding (in-order retire; 2 newer slices = 4 loads;
            // epilogue sq loads in the queue only make this conservative).
            if (last && kkc == 6)      asm volatile("s_waitcnt vmcnt(2)" ::: "memory");
            else if (last && kkc == 7) asm volatile("s_waitcnt vmcnt(0)" ::: "memory");
            else                       asm volatile("s_waitcnt vmcnt(4)" ::: "memory");
            __builtin_amdgcn_s_barrier();
            __builtin_amdgcn_sched_barrier(0);

            const ushort_t* lA = lds[kkc & 3];
            const ushort_t* lB = lds[kkc & 3] + 4096;
            short8 af[4], bf[2];
#pragma unroll
            for (int mi = 0; mi < 4; ++mi)
                af[mi] = *(const short8*)(lA + (a0 + mi) * 512 + laneoff);
#pragma unroll
            for (int ni = 0; ni < 2; ++ni)
                bf[ni] = *(const short8*)(lB + (b0 + ni) * 512 + laneoff);

            // issue stage of slice g+3 into buf (g+3)&3 (consumed at phase
            // g-1; all waves passed this phase's barrier after reading it)
            if (!last || kkc < 5) {
                stage1(sgA, sgB, s_kk, lds[(kkc + 3) & 3], wave, lane);
                ADV_STAGE();
            }

            __builtin_amdgcn_s_setprio(1);
#pragma unroll
            for (int mi = 0; mi < 4; ++mi)
#pragma unroll
                for (int ni = 0; ni < 2; ++ni)
                    accv[mi][ni] = __builtin_amdgcn_mfma_f32_16x16x32_bf16(
                        af[mi], bf[ni], accv[mi][ni], 0, 0, 0);
            __builtin_amdgcn_s_setprio(0);
        }

        // ---- epilogue for (ti, tj). C/D: col = lane&15, row = quad*4+reg.
        const int arow0 = ti * TILE, brow0 = tj * TILE;
        float nsj[2];
#pragma unroll
        for (int ni = 0; ni < 2; ++ni)
            nsj[ni] = -c2 * sq[brow0 + wcol + ni * 16 + l15];
        floatx4 nsi4[4];
#pragma unroll
        for (int mi = 0; mi < 4; ++mi) {
            const float4 sv = *(const float4*)&sq[arow0 + wrow + mi * 16 + quad * 4];
            nsi4[mi][0] = -c2 * sv.x; nsi4[mi][1] = -c2 * sv.y;
            nsi4[mi][2] = -c2 * sv.z; nsi4[mi][3] = -c2 * sv.w;
        }
        floatx4 sum4 = (floatx4)0.f;
#pragma unroll
        for (int mi = 0; mi < 4; ++mi) {
#pragma unroll
            for (int ni = 0; ni < 2; ++ni) {
                const floatx4 addv = nsi4[mi] + (floatx4)nsj[ni];
                floatx4 arg = twoc2 * accv[mi][ni] + addv;
                floatx4 tt;
#pragma unroll
                for (int r = 0; r < 4; ++r) tt[r] = exp2f(fminf(arg[r], 0.f));
                const floatx4 t2 = tt * tt, t4 = t2 * t2, t8 = t4 * t4, t16 = t8 * t8;
                sum4 += (tt + t2) + (t4 + t8) + t16;
            }
        }
        const float fsum = (sum4[0] + sum4[1]) + (sum4[2] + sum4[3]);
        const double contrib = ((ti == tj) ? 1.0 : 2.0) * (double)fsum;
        if (tj < NT_HALF)       lxx += contrib;   // block-uniform branches
        else if (ti < NT_HALF)  lxy += contrib;
        else                    lyy += contrib;

        // advance compute tile
        ++tj; if (tj == NT) { ++ti; tj = ti; }
    }
#undef ADV_STAGE

    // ---- block reduction + finalize ----
#pragma unroll
    for (int off = 32; off > 0; off >>= 1) {
        lxx += __shfl_xor(lxx, off);
        lxy += __shfl_xor(lxy, off);
        lyy += __shfl_xor(lyy, off);
    }
    if (lane == 0) { redw[wave][0] = lxx; redw[wave][1] = lxy; redw[wave][2] = lyy; }
    __syncthreads();
    if (t == 0) {
        double sxx = 0.0, sxy = 0.0, syy = 0.0;
#pragma unroll
        for (int wv = 0; wv < 8; ++wv) {
            sxx += redw[wv][0]; sxy += redw[wv][1]; syy += redw[wv][2];
        }
        if (sxx != 0.0) atomicAdd(&acc[0], sxx);
        if (sxy != 0.0) atomicAdd(&acc[1], sxy);
        if (syy != 0.0) atomicAdd(&acc[2], syy);
        __threadfence();  // release region adds before counter bump
        const unsigned old = atomicAdd(cnt, 1u);
        // counter starts at 0xAAAAAAAA (ws poison) or 0 — accept either
        if (old == (0xAAAAAAAAu + (unsigned)(NCHUNK - 1)) ||
            old == (unsigned)(NCHUNK - 1)) {
            const double xx = atomicAdd(&acc[0], 0.0);  // coherent reads
            const double xy = atomicAdd(&acc[1], 0.0);
            const double yy = atomicAdd(&acc[2], 0.0);
            out[0] = (float)((xx + yy - xy) *
                             (1.0 / ((double)N_HALF * (double)N_HALF)));
        }
    }
}

extern "C" void kernel_launch(void* const* d_in, const int* in_sizes, int n_in,
                              void* d_out, int out_size, void* d_ws, size_t ws_size,
                              hipStream_t stream) {
    const float* X = (const float*)d_in[0];
    const float* Y = (const float*)d_in[1];
    char* ws = (char*)d_ws;
    float* sq        = (float*)ws;               // 8192 f32  [0, 32768)
    float* colsum_r  = (float*)(ws + 32768);     // 8*256 f32 [32768, 40960)
    float* Ssum_r    = (float*)(ws + 40960);     // 8 f32     [40960, 40992)
    unsigned* cnt    = (unsigned*)(ws + 40992);  // 1 u32
    double* acc      = (double*)(ws + 41000);    // 3 f64 (8-aligned)
    float* c2ws      = (float*)(ws + 41024);     // 1 f32
    float* out = (float*)d_out;

    hipLaunchKernelGGL(k_prep, dim3(512), dim3(256), 0, stream,
                       X, Y, sq, colsum_r, Ssum_r);
    hipLaunchKernelGGL(k_bw, dim3(1), dim3(256), 0, stream,
                       colsum_r, Ssum_r, c2ws);
    hipLaunchKernelGGL(k_gram, dim3(NCHUNK), dim3(512), 0, stream,
                       sq, c2ws, acc, cnt, out);
}